// Round 2
// baseline (550.966 us; speedup 1.0000x reference)
//
#include <hip/hip_runtime.h>

// GCN 2-layer forward via device-built CSR (dst-sorted) + gather.
// out[d] = dinv[d]*( sum_{e:dst=d} g[src] + g[d] ) + b,  g = (features)*dinv

#define SCAN_B 512

__global__ void k_deg(const int* __restrict__ dst, int* __restrict__ degi, int E) {
    int e = blockIdx.x * blockDim.x + threadIdx.x;
    if (e < E) atomicAdd(&degi[dst[e]], 1);
}

// dinv = rsqrt(deg+1); h1 = x @ W1; g1 = h1 * dinv
__global__ void k_dense1(const float* __restrict__ x, const float* __restrict__ W1,
                         const int* __restrict__ degi, float* __restrict__ dinv,
                         float* __restrict__ g1, int N) {
    __shared__ float sW[48];   // W1 row-major [3][16]
    if (threadIdx.x < 48) sW[threadIdx.x] = W1[threadIdx.x];
    __syncthreads();
    int i = blockIdx.x * blockDim.x + threadIdx.x;
    if (i >= N) return;
    float di = rsqrtf((float)(degi[i] + 1));   // +1 self-loop
    dinv[i] = di;
    float x0 = x[3*i], x1 = x[3*i+1], x2 = x[3*i+2];
#pragma unroll
    for (int k = 0; k < 16; ++k) {
        float h = x0 * sW[k] + x1 * sW[16 + k] + x2 * sW[32 + k];
        g1[16*i + k] = h * di;
    }
}

// per-block inclusive scan of degi -> off[i+1] (local), block sums -> bsum
__global__ void k_scan1(const int* __restrict__ degi, int* __restrict__ off,
                        int* __restrict__ bsum, int N) {
    __shared__ int s[SCAN_B];
    int tid = threadIdx.x;
    int gid = blockIdx.x * SCAN_B + tid;
    s[tid] = (gid < N) ? degi[gid] : 0;
    __syncthreads();
    for (int d = 1; d < SCAN_B; d <<= 1) {
        int t = (tid >= d) ? s[tid - d] : 0;
        __syncthreads();
        s[tid] += t;
        __syncthreads();
    }
    if (gid < N) off[gid + 1] = s[tid];
    if (tid == SCAN_B - 1) bsum[blockIdx.x] = s[tid];
}

// exclusive scan of block sums (nb <= 1024), one block
__global__ void k_scan2(int* __restrict__ bsum, int nb) {
    __shared__ int s[1024];
    int tid = threadIdx.x;
    int v = (tid < nb) ? bsum[tid] : 0;
    s[tid] = v;
    __syncthreads();
    for (int d = 1; d < 1024; d <<= 1) {
        int t = (tid >= d) ? s[tid - d] : 0;
        __syncthreads();
        s[tid] += t;
        __syncthreads();
    }
    if (tid < nb) bsum[tid] = s[tid] - v;  // exclusive
}

// finalize off (global inclusive) and cursor = exclusive offsets
__global__ void k_scan3(const int* __restrict__ degi, int* __restrict__ off,
                        const int* __restrict__ bsum, int* __restrict__ cursor, int N) {
    int gid = blockIdx.x * blockDim.x + threadIdx.x;
    if (gid == 0) off[0] = 0;
    if (gid < N) {
        int incl = off[gid + 1] + bsum[gid / SCAN_B];
        off[gid + 1] = incl;
        cursor[gid] = incl - degi[gid];
    }
}

__global__ void k_fill(const int* __restrict__ src, const int* __restrict__ dst,
                       int* __restrict__ cursor, int* __restrict__ csr, int E) {
    int e = blockIdx.x * blockDim.x + threadIdx.x;
    if (e < E) {
        int pos = atomicAdd(&cursor[dst[e]], 1);
        csr[pos] = src[e];
    }
}

// one wave (64 lanes) per node: e4 = lane>>4 edge slot, k = lane&15 feature.
// Fused: accumulate neighbors, +self, *dinv, +b1, relu, @W2, *dinv -> g2[2]
__global__ void k_gather1(const int* __restrict__ off, const int* __restrict__ csr,
                          const float* __restrict__ g1, const float* __restrict__ dinv,
                          const float* __restrict__ b1, const float* __restrict__ W2,
                          float* __restrict__ g2, int N) {
    int gtid = blockIdx.x * blockDim.x + threadIdx.x;
    int node = gtid >> 6;
    if (node >= N) return;
    int lane = threadIdx.x & 63;
    int e4 = lane >> 4, k = lane & 15;
    int s0 = off[node], s1 = off[node + 1];
    float sum = 0.f;
    for (int j = s0 + e4; j < s1; j += 4) {
        int s = csr[j];
        sum += g1[16 * s + k];
    }
    // reduce across the 4 edge slots (lane bits 4,5)
    sum += __shfl_xor(sum, 16);
    sum += __shfl_xor(sum, 32);
    float di = dinv[node];
    float t = fmaxf((sum + g1[16 * node + k]) * di + b1[k], 0.f);
    float v0 = t * W2[2 * k];
    float v1 = t * W2[2 * k + 1];
    // reduce across the 16 features (lane bits 0..3)
#pragma unroll
    for (int m = 1; m < 16; m <<= 1) {
        v0 += __shfl_xor(v0, m);
        v1 += __shfl_xor(v1, m);
    }
    if (lane == 0) ((float2*)g2)[node] = make_float2(v0 * di, v1 * di);
}

// one thread per node: accumulate 2 feats over neighbors, +self, log_softmax
__global__ void k_gather2(const int* __restrict__ off, const int* __restrict__ csr,
                          const float* __restrict__ g2, const float* __restrict__ dinv,
                          const float* __restrict__ b2, float* __restrict__ out, int N) {
    int i = blockIdx.x * blockDim.x + threadIdx.x;
    if (i >= N) return;
    int s0 = off[i], s1 = off[i + 1];
    float a0 = 0.f, a1 = 0.f;
    for (int j = s0; j < s1; ++j) {
        float2 v = ((const float2*)g2)[csr[j]];
        a0 += v.x; a1 += v.y;
    }
    float2 self = ((const float2*)g2)[i];
    float di = dinv[i];
    float o0 = (a0 + self.x) * di + b2[0];
    float o1 = (a1 + self.y) * di + b2[1];
    float m = fmaxf(o0, o1);
    float lse = m + logf(expf(o0 - m) + expf(o1 - m));
    ((float2*)out)[i] = make_float2(o0 - lse, o1 - lse);
}

extern "C" void kernel_launch(void* const* d_in, const int* in_sizes, int n_in,
                              void* d_out, int out_size, void* d_ws, size_t ws_size,
                              hipStream_t stream) {
    const float* x  = (const float*)d_in[0];
    const int*   ei = (const int*)d_in[1];   // [2, E] int32 (harness-converted)
    const float* W1 = (const float*)d_in[2];
    const float* b1 = (const float*)d_in[3];
    const float* W2 = (const float*)d_in[4];
    const float* b2 = (const float*)d_in[5];
    float* out = (float*)d_out;

    const int N = in_sizes[0] / 3;
    const int E = in_sizes[1] / 2;
    const int* src = ei;
    const int* dst = ei + E;

    // ws layout (int units):
    // [degi N][off N+8][cursor N][bsum 1024][csr E][dinv N][g1 16N][g2 2N]
    int* degi   = (int*)d_ws;
    int* off    = degi + N;
    int* cursor = off + N + 8;
    int* bsum   = cursor + N;
    int* csr    = bsum + 1024;
    float* dinv = (float*)(csr + E);
    float* g1   = dinv + N;
    float* g2   = g1 + (size_t)16 * N;

    hipMemsetAsync(degi, 0, (size_t)N * 4, stream);

    int nbE = (E + 255) / 256;
    k_deg<<<nbE, 256, 0, stream>>>(dst, degi, E);

    int nbN = (N + 255) / 256;
    k_dense1<<<nbN, 256, 0, stream>>>(x, W1, degi, dinv, g1, N);

    int nbS = (N + SCAN_B - 1) / SCAN_B;   // 196 <= 1024
    k_scan1<<<nbS, SCAN_B, 0, stream>>>(degi, off, bsum, N);
    k_scan2<<<1, 1024, 0, stream>>>(bsum, nbS);
    k_scan3<<<nbN, 256, 0, stream>>>(degi, off, bsum, cursor, N);

    k_fill<<<nbE, 256, 0, stream>>>(src, dst, cursor, csr, E);

    long long t1 = (long long)N * 64;
    int nbG = (int)((t1 + 255) / 256);
    k_gather1<<<nbG, 256, 0, stream>>>(off, csr, g1, dinv, b1, W2, g2, N);

    k_gather2<<<nbN, 256, 0, stream>>>(off, csr, g2, dinv, b2, out, N);
}